// Round 17
// baseline (61.727 us; speedup 1.0000x reference)
//
#include <hip/hip_runtime.h>

#define BB 128
#define LL 336
#define CC 862
#define PRED 96
#define WIN 12
#define S_IN 28
#define S_OUT 8
#define CT 128
#define NTILES 7                       // ceil(862/128)
#define NCH 14                         // s-chunks of 2 windows (24 rows)
#define LSTR 25                        // LDS per-channel stride (odd -> conflict-free reads)

#define SQRT12F 3.4641016151377544f

// -Sb(t)/sqrt(12), Sb(t) = 2*sum_{k=1..5} sin(pi*k*t/6)   (exact closed forms)
__device__ const float COEFP[12] = {
    0.0f, -2.1547005383792515f, 0.0f, -0.5773502691896258f,
    0.0f, -0.15470053837925146f, 0.0f, 0.15470053837925146f,
    0.0f,  0.5773502691896258f, 0.0f,  2.1547005383792515f
};

// ---- prep kernels ----

// packed weights: wpk[((p*S_IN + s)*CC + c)*2 + {0,1}] = {wA, wP}[c][p][s]
__global__ void prep_wpk(const float* __restrict__ wA, const float* __restrict__ wP,
                         float* __restrict__ wpk) {
    int i = blockIdx.x * 256 + threadIdx.x;          // i = (p*S_IN + s)*CC + c
    if (i >= S_OUT * S_IN * CC) return;
    int c  = i % CC;
    int ps = i / CC;
    int s  = ps % S_IN;
    int p  = ps / S_IN;
    int src = (c * S_OUT + p) * S_IN + s;
    wpk[2 * i]     = wA[src];
    wpk[2 * i + 1] = wP[src];
}

__global__ void prep_mcoef(const float* __restrict__ wA, float* __restrict__ mcoefT) {
    int i = blockIdx.x * 256 + threadIdx.x;          // [p][c]
    if (i >= S_OUT * CC) return;
    int c = i % CC;
    int p = i / CC;
    float s = 0.f;
    for (int k = 0; k < S_IN; ++k) s += wA[(c * S_OUT + p) * S_IN + k];
    mcoefT[i] = 1.0f - s;
}

__global__ void prep_bias(const float* __restrict__ bA, const float* __restrict__ bP,
                          float* __restrict__ biasv) {
    int i = blockIdx.x * 256 + threadIdx.x;          // [t][p][c]
    if (i >= 12 * S_OUT * CC) return;
    int c = i % CC;
    int tp = i / CC;
    int p = tp % S_OUT;
    int t = tp / S_OUT;
    float v = COEFP[t] * bP[c * S_OUT + p];
    if (t == 0) v += SQRT12F * bA[c * S_OUT + p];
    biasv[i] = v;
}

// ---- fused main kernel ----
// r16 (CT=128: 512-B granules, the lever that broke the 3 TB/s DRAM-pattern wall)
// + double-buffered LDS: ONE barrier per chunk (was 2) and loads issued TWO
// chunks ahead (full iteration of latency budget vs ~200 cy before).
// launch_bounds(512,6): VGPR cap ~84 -> up to 24 waves/CU with 25.9 KB LDS.

template <bool TRANS>
__global__ __launch_bounds__(512, 6) void fused17(
    const float* __restrict__ x,
    const float* __restrict__ wpk,
    const float* __restrict__ mcoefT, const float* __restrict__ biasv,
    const float* __restrict__ wA_raw, const float* __restrict__ wP_raw,
    const float* __restrict__ bAr, const float* __restrict__ bPr,
    float* __restrict__ out)
{
    __shared__ float sl[2][CT * LSTR];   // 2 x 12800 B

    const int b   = blockIdx.y;
    const int c0  = blockIdx.x * CT;
    const int NC  = min(CT, CC - c0);  // 128 or 94 (even)
    const int tid = threadIdx.x;       // 0..511

    // staging map: one wave = one full 512-B row segment (64 float2)
    const int slot  = tid & 63;
    const int rbase = tid >> 6;        // 0..7
    const int col   = 2 * slot;
    const int csrc  = (col + 1 < NC) ? col : (NC - 2);
    const float* xb = x + ((size_t)b * LL) * CC + c0 + csrc;

    // compute map
    const int cc = tid & 127;
    const int pg = tid >> 7;           // 0..3 -> p = pg, pg+4
    const int c  = c0 + cc;
    const bool act = (cc < NC);
    const int cl = act ? c : (CC - 1);

    float2 vbuf[3];

    // ---- prologue: chunk 0 -> sl[0]; issue chunk 1 loads ----
    #pragma unroll
    for (int kk = 0; kk < 3; ++kk) {
        const int r = rbase + 8 * kk;
        vbuf[kk] = *reinterpret_cast<const float2*>(xb + (size_t)r * CC);
    }
    #pragma unroll
    for (int kk = 0; kk < 3; ++kk) {
        const int r = rbase + 8 * kk;
        sl[0][col * LSTR + r]       = vbuf[kk].x;
        sl[0][(col + 1) * LSTR + r] = vbuf[kk].y;
    }
    #pragma unroll
    for (int kk = 0; kk < 3; ++kk) {
        const int r = rbase + 8 * kk;
        vbuf[kk] = *reinterpret_cast<const float2*>(xb + (size_t)(24 + r) * CC);
    }
    __syncthreads();

    float A0[2] = {0.f, 0.f}, A6[2] = {0.f, 0.f};
    float Au[2][5] = {{0.f,0.f,0.f,0.f,0.f},{0.f,0.f,0.f,0.f,0.f}};
    float Pv[2][5] = {{0.f,0.f,0.f,0.f,0.f},{0.f,0.f,0.f,0.f,0.f}};
    float msum = 0.f;
    float sw[2] = {0.f, 0.f};          // fallback only

    const float2* wq = reinterpret_cast<const float2*>(wpk);

    #pragma unroll 1
    for (int k = 0; k < NCH; ++k) {
        // vbuf holds chunk k+1: write it to the other buffer (readers of that
        // buffer finished at iter k-1's barrier)
        if (k + 1 < NCH) {
            float* d = sl[(k + 1) & 1];
            #pragma unroll
            for (int kk = 0; kk < 3; ++kk) {
                const int r = rbase + 8 * kk;
                d[col * LSTR + r]       = vbuf[kk].x;
                d[(col + 1) * LSTR + r] = vbuf[kk].y;
            }
        }
        // issue chunk k+2 loads: waitcnt lands at next iter's LDS write,
        // a full compute+barrier away
        if (k + 2 < NCH) {
            const float* xn = xb + (size_t)(k + 2) * 24 * CC;
            #pragma unroll
            for (int kk = 0; kk < 3; ++kk) {
                const int r = rbase + 8 * kk;
                vbuf[kk] = *reinterpret_cast<const float2*>(xn + (size_t)r * CC);
            }
        }

        // compute the 2 windows staged in sl[k&1]
        const float* sb = sl[k & 1];
        #pragma unroll
        for (int w = 0; w < 2; ++w) {
            const int s = 2 * k + w;
            float x12[12];
            #pragma unroll
            for (int t = 0; t < 12; ++t) x12[t] = sb[cc * LSTR + w * 12 + t];

            const float u1 = x12[1] + x12[11], v1 = x12[1] - x12[11];
            const float u2 = x12[2] + x12[10], v2 = x12[2] - x12[10];
            const float u3 = x12[3] + x12[9],  v3 = x12[3] - x12[9];
            const float u4 = x12[4] + x12[8],  v4 = x12[4] - x12[8];
            const float u5 = x12[5] + x12[7],  v5 = x12[5] - x12[7];
            msum += (x12[0] + x12[6]) + ((u1 + u2) + (u3 + u4) + u5);

            #pragma unroll
            for (int e = 0; e < 2; ++e) {
                const int p = pg + 4 * e;
                float wa, wpv;
                if (TRANS) {
                    const float2 wv = wq[(size_t)(p * S_IN + s) * CC + cl];
                    wa = wv.x; wpv = wv.y;
                } else {
                    wa  = wA_raw[((size_t)cl * S_OUT + p) * S_IN + s];
                    wpv = wP_raw[((size_t)cl * S_OUT + p) * S_IN + s];
                    sw[e] += wa;
                }
                A0[e] = fmaf(wa, x12[0], A0[e]);
                A6[e] = fmaf(wa, x12[6], A6[e]);
                Au[e][0] = fmaf(wa, u1, Au[e][0]);
                Au[e][1] = fmaf(wa, u2, Au[e][1]);
                Au[e][2] = fmaf(wa, u3, Au[e][2]);
                Au[e][3] = fmaf(wa, u4, Au[e][3]);
                Au[e][4] = fmaf(wa, u5, Au[e][4]);
                Pv[e][0] = fmaf(wpv, v1, Pv[e][0]);
                Pv[e][1] = fmaf(wpv, v2, Pv[e][1]);
                Pv[e][2] = fmaf(wpv, v3, Pv[e][2]);
                Pv[e][3] = fmaf(wpv, v4, Pv[e][3]);
                Pv[e][4] = fmaf(wpv, v5, Pv[e][4]);
            }
        }
        __syncthreads();               // single barrier per chunk
    }

    if (!act) return;

    const float mean = msum * (1.0f / LL);

    #pragma unroll
    for (int e = 0; e < 2; ++e) {
        const int p = pg + 4 * e;
        float mc, bias[12];
        if (TRANS) {
            mc = mcoefT[p * CC + c];
            #pragma unroll
            for (int t = 0; t < 12; ++t)
                bias[t] = biasv[(size_t)(t * S_OUT + p) * CC + c];
        } else {
            mc = 1.0f - sw[e];
            const float ba = bAr[c * S_OUT + p], bp = bPr[c * S_OUT + p];
            #pragma unroll
            for (int t = 0; t < 12; ++t)
                bias[t] = COEFP[t] * bp + (t == 0 ? SQRT12F * ba : 0.f);
        }
        const float mb = mean * mc;
        float* ob = out + ((size_t)b * PRED + p * WIN) * CC + c;
        ob[0]              = A0[e] + mb + bias[0];
        ob[(size_t)6 * CC] = A6[e] + mb + bias[6];
        #pragma unroll
        for (int t = 1; t <= 5; ++t) {
            ob[(size_t)t * CC]        = 0.5f * (Au[e][t-1] + Pv[e][t-1]) + mb + bias[t];
            ob[(size_t)(12 - t) * CC] = 0.5f * (Au[e][t-1] - Pv[e][t-1]) + mb + bias[12 - t];
        }
    }
}

extern "C" void kernel_launch(void* const* d_in, const int* in_sizes, int n_in,
                              void* d_out, int out_size, void* d_ws, size_t ws_size,
                              hipStream_t stream) {
    const float* x  = (const float*)d_in[0];
    const float* wA = (const float*)d_in[1];
    const float* bA = (const float*)d_in[2];
    const float* wP = (const float*)d_in[3];
    const float* bP = (const float*)d_in[4];
    float* out = (float*)d_out;

    const size_t nW  = (size_t)S_OUT * S_IN * CC;    // 193088
    const size_t nM  = (size_t)S_OUT * CC;           // 6896
    const size_t nBv = (size_t)12 * S_OUT * CC;      // 82752
    const size_t need = (2 * nW + nM + nBv) * sizeof(float);

    dim3 grid(NTILES, BB);

    if (ws_size >= need) {
        float* wpk    = (float*)d_ws;                // 2*nW floats
        float* mcoefT = wpk + 2 * nW;
        float* biasv  = mcoefT + nM;

        prep_wpk<<<(int)((nW + 255) / 256), 256, 0, stream>>>(wA, wP, wpk);
        prep_mcoef<<<(int)((nM + 255) / 256), 256, 0, stream>>>(wA, mcoefT);
        prep_bias<<<(int)((nBv + 255) / 256), 256, 0, stream>>>(bA, bP, biasv);

        fused17<true><<<grid, 512, 0, stream>>>(
            x, wpk, mcoefT, biasv,
            nullptr, nullptr, nullptr, nullptr, out);
    } else {
        fused17<false><<<grid, 512, 0, stream>>>(
            x, nullptr, nullptr, nullptr,
            wA, wP, bA, bP, out);
    }
}